// Round 1
// baseline (116.274 us; speedup 1.0000x reference)
//
#include <hip/hip_runtime.h>
#include <math.h>

// Problem constants (match reference setup_inputs)
#define VOCAB   32000
#define D_MODEL 512
#define BATCH   8
#define SEQ     4096

// -log2(10000)/256  : invfreq(d) = 10000^(-d/256) = exp2f(d * NEG_L2_1E4_O256)
#define NEG_L2_1E4_O256 (-13.287712379549449f / 256.0f)

// One block per sequence position s (4096 blocks), 128 threads.
// Thread t owns float4 column t (d = 4t..4t+3). PE computed once per (s,d),
// reused across all 8 batches (8x fewer sincos than naive).
__global__ __launch_bounds__(128) void emb_pe_kernel(
    const int*   __restrict__ tokens,   // [BATCH, SEQ] int32
    const float* __restrict__ table,    // [VOCAB, D_MODEL] fp32
    float*       __restrict__ out)      // [BATCH, SEQ, D_MODEL] fp32
{
    const int s   = blockIdx.x;      // 0..SEQ-1
    const int tid = threadIdx.x;     // 0..127
    const int d0  = tid << 2;        // first of 4 d-indices

    // --- positional encoding for (s, d0..d0+3) ---
    const float sf = (float)s;
    float pe[4];
#pragma unroll
    for (int j = 0; j < 4; ++j) {
        const int d = d0 + j;
        // angle = s * 10000^(-d/256)
        const float invf = exp2f((float)d * NEG_L2_1E4_O256);
        const float ang  = sf * invf;
        pe[j] = (d & 1) ? cosf(ang) : sinf(ang);
    }

    const float4* tbl4 = (const float4*)table;
    float4*       out4 = (float4*)out;

    // Prefetch all 8 tokens (block-uniform -> scalar loads)
    int tok[BATCH];
#pragma unroll
    for (int b = 0; b < BATCH; ++b)
        tok[b] = tokens[b * SEQ + s];

#pragma unroll
    for (int b = 0; b < BATCH; ++b) {
        float4 e = tbl4[tok[b] * (D_MODEL / 4) + tid];
        e.x += pe[0];
        e.y += pe[1];
        e.z += pe[2];
        e.w += pe[3];
        out4[((size_t)b * SEQ + s) * (D_MODEL / 4) + tid] = e;
    }
}

extern "C" void kernel_launch(void* const* d_in, const int* in_sizes, int n_in,
                              void* d_out, int out_size, void* d_ws, size_t ws_size,
                              hipStream_t stream) {
    const int*   tokens = (const int*)d_in[0];    // [8,4096] int32
    const float* table  = (const float*)d_in[1];  // [32000,512] fp32
    float*       out    = (float*)d_out;          // [8,4096,512] fp32

    emb_pe_kernel<<<SEQ, 128, 0, stream>>>(tokens, table, out);
}